// Round 3
// baseline (780.275 us; speedup 1.0000x reference)
//
#include <hip/hip_runtime.h>
#include <float.h>
#include <math.h>

#define BATCH 8
#define NPTS 4096
#define KNN 10
#define BN (BATCH * NPTS)          // 32768 points per cloud
#define TPB 1024                   // 16 waves
#define WAVES 16
#define Q 4                        // queries per lane
#define QPB (64 * Q)               // 256 queries per block
#define HALF_N (NPTS / 2)          // 2048 candidates per block (half cloud)
#define SEGC (HALF_N / WAVES)      // 128 candidates per wave
#define KB_STRIDE (Q * KNN + 1)    // 41: odd stride -> 2-way banks (free)

// per-half packed top-10 keys: [cloud][batch][half][j][q] = 5.24 MB
__device__ float g_keys[2 * BATCH * 2 * KNN * NPTS];

__device__ inline float med3f(float x, float a, float b) {
    return __builtin_amdgcn_fmed3f(x, a, b);
}

// branchless sorted insert of key into ascending k[0..9] (drop largest);
// all 9 med3 read pre-insert values -> mutually independent
#define INSERT(karr, key)                                              \
    do {                                                               \
        _Pragma("unroll")                                              \
        for (int _j = KNN - 1; _j >= 1; --_j)                          \
            karr[_j] = med3f((key), karr[_j - 1], karr[_j]);           \
        karr[0] = fminf((key), karr[0]);                               \
    } while (0)

// distance + pack + 4 inserts for one candidate float4 _p at global index _gi
#define PROC(_p, _gi)                                                  \
    do {                                                               \
        float _d0 = fmaf((_p).z, a0z, fmaf((_p).y, a0y, fmaf((_p).x, a0x, (_p).w))); \
        float _d1 = fmaf((_p).z, a1z, fmaf((_p).y, a1y, fmaf((_p).x, a1x, (_p).w))); \
        float _d2 = fmaf((_p).z, a2z, fmaf((_p).y, a2y, fmaf((_p).x, a2x, (_p).w))); \
        float _d3 = fmaf((_p).z, a3z, fmaf((_p).y, a3y, fmaf((_p).x, a3x, (_p).w))); \
        float _k0 = __uint_as_float((__float_as_uint(_d0) & 0xFFFFF000u) | (_gi)); \
        float _k1 = __uint_as_float((__float_as_uint(_d1) & 0xFFFFF000u) | (_gi)); \
        float _k2 = __uint_as_float((__float_as_uint(_d2) & 0xFFFFF000u) | (_gi)); \
        float _k3 = __uint_as_float((__float_as_uint(_d3) & 0xFFFFF000u) | (_gi)); \
        INSERT(kq0, _k0);                                              \
        INSERT(kq1, _k1);                                              \
        INSERT(kq2, _k2);                                              \
        INSERT(kq3, _k3);                                              \
    } while (0)

#define PROC4(P, _gi)                                                  \
    do {                                                               \
        PROC(P##0, (_gi) + 0);                                         \
        PROC(P##1, (_gi) + 1);                                         \
        PROC(P##2, (_gi) + 2);                                         \
        PROC(P##3, (_gi) + 3);                                         \
    } while (0)

#define LOAD4(P, _off)                                                 \
    do {                                                               \
        P##0 = pts[(_off) + 0]; P##1 = pts[(_off) + 1];                \
        P##2 = pts[(_off) + 2]; P##3 = pts[(_off) + 3];                \
    } while (0)

// publish this wave's 4 key arrays to merge-buffer row `row`
#define WRITEKEYS(row)                                                 \
    do {                                                               \
        float* _dst = keybuf + ((row) * 64 + lane) * KB_STRIDE;        \
        _Pragma("unroll")                                              \
        for (int _j = 0; _j < KNN; ++_j) {                             \
            _dst[_j] = kq0[_j];            _dst[KNN + _j] = kq1[_j];   \
            _dst[2 * KNN + _j] = kq2[_j];  _dst[3 * KNN + _j] = kq3[_j]; \
        }                                                              \
    } while (0)

// merge buffer row `row` into this wave's key arrays
#define MERGEKEYS(row)                                                 \
    do {                                                               \
        const float* _src = keybuf + ((row) * 64 + lane) * KB_STRIDE;  \
        _Pragma("unroll")                                              \
        for (int _j = 0; _j < KNN; ++_j) {                             \
            float _s0 = _src[_j], _s1 = _src[KNN + _j];                \
            float _s2 = _src[2 * KNN + _j], _s3 = _src[3 * KNN + _j];  \
            INSERT(kq0, _s0); INSERT(kq1, _s1);                        \
            INSERT(kq2, _s2); INSERT(kq3, _s3);                        \
        }                                                              \
    } while (0)

// Eigenvector of smallest eigenvalue of symmetric 3x3
__device__ inline void smallest_eigvec(float a00, float a01, float a02,
                                       float a11, float a12, float a22,
                                       float& vx, float& vy, float& vz) {
    float p1 = a01 * a01 + a02 * a02 + a12 * a12;
    float q = (a00 + a11 + a22) * (1.0f / 3.0f);
    float b00 = a00 - q, b11 = a11 - q, b22 = a22 - q;
    float p2 = b00 * b00 + b11 * b11 + b22 * b22 + 2.0f * p1;
    float p = sqrtf(p2 * (1.0f / 6.0f));
    if (p < 1e-20f) { vx = 1.0f; vy = 0.0f; vz = 0.0f; return; }
    float ip = 1.0f / p;
    float c00 = b00 * ip, c01 = a01 * ip, c02 = a02 * ip;
    float c11 = b11 * ip, c12 = a12 * ip, c22 = b22 * ip;
    float detB = c00 * (c11 * c22 - c12 * c12)
               - c01 * (c01 * c22 - c12 * c02)
               + c02 * (c01 * c12 - c11 * c02);
    float r = 0.5f * detB;
    r = fminf(1.0f, fmaxf(-1.0f, r));
    float phi = acosf(r) * (1.0f / 3.0f);
    float lmin = q + 2.0f * p * cosf(phi + 2.0943951023931953f);

    float m00 = a00 - lmin, m11 = a11 - lmin, m22 = a22 - lmin;
    float r0x = m00, r0y = a01, r0z = a02;
    float r1x = a01, r1y = m11, r1z = a12;
    float r2x = a02, r2y = a12, r2z = m22;
    float c0x = r0y * r1z - r0z * r1y, c0y = r0z * r1x - r0x * r1z, c0z = r0x * r1y - r0y * r1x;
    float c1x = r0y * r2z - r0z * r2y, c1y = r0z * r2x - r0x * r2z, c1z = r0x * r2y - r0y * r2x;
    float c2x = r1y * r2z - r1z * r2y, c2y = r1z * r2x - r1x * r2z, c2z = r1x * r2y - r1y * r2x;
    float n0 = c0x * c0x + c0y * c0y + c0z * c0z;
    float n1 = c1x * c1x + c1y * c1y + c1z * c1z;
    float n2 = c2x * c2x + c2y * c2y + c2z * c2z;
    float bx = c0x, by = c0y, bz = c0z, bnm = n0;
    if (n1 > bnm) { bx = c1x; by = c1y; bz = c1z; bnm = n1; }
    if (n2 > bnm) { bx = c2x; by = c2y; bz = c2z; bnm = n2; }
    if (bnm < 1e-30f) { vx = 1.0f; vy = 0.0f; vz = 0.0f; return; }
    float inv = rsqrtf(bnm);
    vx = bx * inv; vy = by * inv; vz = bz * inv;
}

__global__ void zero_out_kernel(float* __restrict__ out) {
    if (threadIdx.x == 0) out[0] = 0.0f;
}

// One block = 256 queries x ONE HALF (2048 candidates) of one cloud of one batch.
// 74.9 KB LDS -> 2 blocks/CU -> 8 waves/SIMD (the occupancy experiment).
// 16 waves; lane l owns queries qbase + l + {0,64,128,192}; wave w scans
// 128 candidates; in-block tree merge 16->1; per-half top-10 keys -> g_keys.
__global__ __launch_bounds__(TPB, 8) void knn_half(
    const float* __restrict__ pred, const float* __restrict__ gt) {
    __shared__ float4 pts[HALF_N + 8];               // 32.9 KB + prefetch pad
    __shared__ float keybuf[4 * 64 * KB_STRIDE];     // 42 KB (4-wave buffer)

    const int b = blockIdx.y;
    const int cloud = blockIdx.z >> 1;
    const int half = blockIdx.z & 1;
    const float* __restrict__ base = (cloud ? gt : pred) + b * 3 * NPTS;
    const int tid = threadIdx.x;
    const int lane = tid & 63;
    const int w = tid >> 6;           // wave id = segment id (0..15)
    const int s0 = w * SEGC;          // wave-uniform LDS segment offset
    const int qbase = blockIdx.x * QPB;
    const int hb = half * HALF_N;     // global candidate offset of this half

    // query coefficients from global (queries may live in the other half);
    // issued before the staging barrier so the latency overlaps staging
    const int q0 = qbase + lane;
    const float a0x = -2.0f * base[q0],       a0y = -2.0f * base[NPTS + q0],       a0z = -2.0f * base[2 * NPTS + q0];
    const float a1x = -2.0f * base[q0 + 64],  a1y = -2.0f * base[NPTS + q0 + 64],  a1z = -2.0f * base[2 * NPTS + q0 + 64];
    const float a2x = -2.0f * base[q0 + 128], a2y = -2.0f * base[NPTS + q0 + 128], a2z = -2.0f * base[2 * NPTS + q0 + 128];
    const float a3x = -2.0f * base[q0 + 192], a3y = -2.0f * base[NPTS + q0 + 192], a3z = -2.0f * base[2 * NPTS + q0 + 192];

    // stage this half (x, y, z, |p|^2)
    for (int i = tid; i < HALF_N; i += TPB) {
        float x = base[hb + i];
        float y = base[NPTS + hb + i];
        float z = base[2 * NPTS + hb + i];
        pts[i] = make_float4(x, y, z, fmaf(x, x, fmaf(y, y, z * z)));
    }
    __syncthreads();

    float kq0[KNN], kq1[KNN], kq2[KNN], kq3[KNN];
#pragma unroll
    for (int j = 0; j < KNN; ++j) { kq0[j] = FLT_MAX; kq1[j] = FLT_MAX; kq2[j] = FLT_MAX; kq3[j] = FLT_MAX; }

    // scan: register double-buffer 4+4 float4, sched_barrier fenced
    {
        const unsigned gb = (unsigned)(hb + s0);     // global index base (12-bit pack)
        float4 A0, A1, A2, A3;
        float4 B0, B1, B2, B3;
        LOAD4(A, s0);
        __builtin_amdgcn_sched_barrier(0);
        for (int c = 0; c < SEGC; c += 8) {
            LOAD4(B, s0 + c + 4);
            __builtin_amdgcn_sched_barrier(0);
            PROC4(A, gb + (unsigned)c);
            __builtin_amdgcn_sched_barrier(0);
            LOAD4(A, s0 + c + 8);     /* last iter reads pad */
            __builtin_amdgcn_sched_barrier(0);
            PROC4(B, gb + (unsigned)c + 4u);
            __builtin_amdgcn_sched_barrier(0);
        }
    }

    // tree merge 16->1 over a 4-wave buffer (level 1 split into 2 sub-phases)
    if (w >= 8 && w < 12) WRITEKEYS(w - 8);
    __syncthreads();
    if (w < 4) MERGEKEYS(w);                 // w merges w+8
    __syncthreads();
    if (w >= 12) WRITEKEYS(w - 12);
    __syncthreads();
    if (w >= 4 && w < 8) MERGEKEYS(w - 4);   // w merges w+8
    __syncthreads();
    if (w >= 4 && w < 8) WRITEKEYS(w - 4);
    __syncthreads();
    if (w < 4) MERGEKEYS(w);                 // w merges w+4
    __syncthreads();
    if (w >= 2 && w < 4) WRITEKEYS(w - 2);
    __syncthreads();
    if (w < 2) MERGEKEYS(w);                 // w merges w+2
    __syncthreads();
    if (w == 1) WRITEKEYS(0);
    __syncthreads();
    if (w == 0) {
        MERGEKEYS(0);                        // wave 0 holds final half top-10s
        const int kb = ((cloud * BATCH + b) * 2 + half) * KNN;
#pragma unroll
        for (int j = 0; j < KNN; ++j) {      // coalesced: lanes write consecutive q
            g_keys[(kb + j) * NPTS + qbase + lane]       = kq0[j];
            g_keys[(kb + j) * NPTS + qbase + 64 + lane]  = kq1[j];
            g_keys[(kb + j) * NPTS + qbase + 128 + lane] = kq2[j];
            g_keys[(kb + j) * NPTS + qbase + 192 + lane] = kq3[j];
        }
    }
}

// one thread per (batch, query): merge the two half top-10s (exact: keys carry
// index bits), gather 10 neighbors per cloud (L3-resident), covariance ->
// smallest eigenvector -> cosine loss; wave-sum + one atomic per wave
__global__ __launch_bounds__(256) void merge_normal_loss(
    const float* __restrict__ pred, const float* __restrict__ gt,
    float* __restrict__ out) {
    const int t = blockIdx.x * 256 + threadIdx.x;    // grid sized exactly BN
    const int b = t >> 12;
    const int q = t & (NPTS - 1);

    float nx[2], ny[2], nz[2];
#pragma unroll
    for (int c = 0; c < 2; ++c) {
        const float* __restrict__ base = (c ? gt : pred) + b * 3 * NPTS;
        const int kb0 = ((c * BATCH + b) * 2 + 0) * KNN;
        const int kb1 = ((c * BATCH + b) * 2 + 1) * KNN;
        float k0[KNN];
#pragma unroll
        for (int j = 0; j < KNN; ++j) k0[j] = g_keys[(kb0 + j) * NPTS + q];
#pragma unroll
        for (int j = 0; j < KNN; ++j) {
            float s = g_keys[(kb1 + j) * NPTS + q];
            INSERT(k0, s);
        }
        float sx = 0.f, sy = 0.f, sz = 0.f;
        float sxx = 0.f, sxy = 0.f, sxz = 0.f;
        float syy = 0.f, syz = 0.f, szz = 0.f;
#pragma unroll
        for (int j = 0; j < KNN; ++j) {
            int idx = (int)(__float_as_uint(k0[j]) & 0xFFFu);
            float x = base[idx];
            float y = base[NPTS + idx];
            float z = base[2 * NPTS + idx];
            sx += x; sy += y; sz += z;
            sxx = fmaf(x, x, sxx); sxy = fmaf(x, y, sxy); sxz = fmaf(x, z, sxz);
            syy = fmaf(y, y, syy); syz = fmaf(y, z, syz); szz = fmaf(z, z, szz);
        }
        const float iK = 1.0f / KNN;
        float mx = sx * iK, my = sy * iK, mz = sz * iK;
        smallest_eigvec(sxx * iK - mx * mx, sxy * iK - mx * my,
                        sxz * iK - mx * mz, syy * iK - my * my,
                        syz * iK - my * mz, szz * iK - mz * mz,
                        nx[c], ny[c], nz[c]);
    }
    float dot = nx[0] * nx[1] + ny[0] * ny[1] + nz[0] * nz[1];
    float npn = sqrtf(nx[0] * nx[0] + ny[0] * ny[0] + nz[0] * nz[0]);
    float ngn = sqrtf(nx[1] * nx[1] + ny[1] * ny[1] + nz[1] * nz[1]);
    float acc = 1.0f - fabsf(dot / fmaxf(npn * ngn, 1e-8f));
    for (int off = 32; off > 0; off >>= 1) acc += __shfl_down(acc, off);
    if ((threadIdx.x & 63) == 0) atomicAdd(out, acc * (1.0f / (float)BN));
}

extern "C" void kernel_launch(void* const* d_in, const int* in_sizes, int n_in,
                              void* d_out, int out_size, void* d_ws, size_t ws_size,
                              hipStream_t stream) {
    const float* pred = (const float*)d_in[0];
    const float* gt = (const float*)d_in[1];
    float* out = (float*)d_out;

    zero_out_kernel<<<1, 64, 0, stream>>>(out);
    dim3 grid(NPTS / QPB, BATCH, 4);  // 16 x 8 x (2 clouds x 2 halves) = 512 blocks = 2/CU
    knn_half<<<grid, TPB, 0, stream>>>(pred, gt);
    merge_normal_loss<<<dim3(BN / 256), 256, 0, stream>>>(pred, gt, out);
}

// Round 4
// 172.963 us; speedup vs baseline: 4.5112x; 4.5112x over previous
//
#include <hip/hip_runtime.h>
#include <float.h>
#include <math.h>

#define BATCH 8
#define NPTS 4096
#define KNN 10
#define BN (BATCH * NPTS)          // 32768 points per cloud
#define TPB 1024                   // 16 waves
#define WAVES 16
#define Q 2                        // queries per lane (keys=20 VGPR: fits 64-VGPR cap)
#define QPB (64 * Q)               // 128 queries per block
#define SEGC (NPTS / WAVES)        // 256 candidates per wave
#define KB_STRIDE (Q * KNN + 1)    // 21: odd stride -> 2-way banks (free)

// module-scope normals buffer (1 MiB)
__device__ float4 g_nrm[2 * BN];

__device__ inline float med3f(float x, float a, float b) {
    return __builtin_amdgcn_fmed3f(x, a, b);
}

// branchless sorted insert of key into ascending k[0..9] (drop largest);
// all 9 med3 read pre-insert values -> mutually independent
#define INSERT(karr, key)                                              \
    do {                                                               \
        _Pragma("unroll")                                              \
        for (int _j = KNN - 1; _j >= 1; --_j)                          \
            karr[_j] = med3f((key), karr[_j - 1], karr[_j]);           \
        karr[0] = fminf((key), karr[0]);                               \
    } while (0)

// distance + pack + 2 inserts for one candidate float4 _p at index _gi
#define PROC(_p, _gi)                                                  \
    do {                                                               \
        float _d0 = fmaf((_p).z, a0z, fmaf((_p).y, a0y, fmaf((_p).x, a0x, (_p).w))); \
        float _d1 = fmaf((_p).z, a1z, fmaf((_p).y, a1y, fmaf((_p).x, a1x, (_p).w))); \
        float _k0 = __uint_as_float((__float_as_uint(_d0) & 0xFFFFF000u) | (_gi)); \
        float _k1 = __uint_as_float((__float_as_uint(_d1) & 0xFFFFF000u) | (_gi)); \
        INSERT(kq0, _k0);                                              \
        INSERT(kq1, _k1);                                              \
    } while (0)

#define PROC2(P, _gi)                                                  \
    do {                                                               \
        PROC(P##0, (_gi) + 0);                                         \
        PROC(P##1, (_gi) + 1);                                         \
    } while (0)

#define LOAD2(P, _off)                                                 \
    do {                                                               \
        P##0 = pts[(_off) + 0]; P##1 = pts[(_off) + 1];                \
    } while (0)

// Eigenvector of smallest eigenvalue of symmetric 3x3
__device__ inline void smallest_eigvec(float a00, float a01, float a02,
                                       float a11, float a12, float a22,
                                       float& vx, float& vy, float& vz) {
    float p1 = a01 * a01 + a02 * a02 + a12 * a12;
    float q = (a00 + a11 + a22) * (1.0f / 3.0f);
    float b00 = a00 - q, b11 = a11 - q, b22 = a22 - q;
    float p2 = b00 * b00 + b11 * b11 + b22 * b22 + 2.0f * p1;
    float p = sqrtf(p2 * (1.0f / 6.0f));
    if (p < 1e-20f) { vx = 1.0f; vy = 0.0f; vz = 0.0f; return; }
    float ip = 1.0f / p;
    float c00 = b00 * ip, c01 = a01 * ip, c02 = a02 * ip;
    float c11 = b11 * ip, c12 = a12 * ip, c22 = b22 * ip;
    float detB = c00 * (c11 * c22 - c12 * c12)
               - c01 * (c01 * c22 - c12 * c02)
               + c02 * (c01 * c12 - c11 * c02);
    float r = 0.5f * detB;
    r = fminf(1.0f, fmaxf(-1.0f, r));
    float phi = acosf(r) * (1.0f / 3.0f);
    float lmin = q + 2.0f * p * cosf(phi + 2.0943951023931953f);

    float m00 = a00 - lmin, m11 = a11 - lmin, m22 = a22 - lmin;
    float r0x = m00, r0y = a01, r0z = a02;
    float r1x = a01, r1y = m11, r1z = a12;
    float r2x = a02, r2y = a12, r2z = m22;
    float c0x = r0y * r1z - r0z * r1y, c0y = r0z * r1x - r0x * r1z, c0z = r0x * r1y - r0y * r1x;
    float c1x = r0y * r2z - r0z * r2y, c1y = r0z * r2x - r0x * r2z, c1z = r0x * r2y - r0y * r2x;
    float c2x = r1y * r2z - r1z * r2y, c2y = r1z * r2x - r1x * r2z, c2z = r1x * r2y - r1y * r2x;
    float n0 = c0x * c0x + c0y * c0y + c0z * c0z;
    float n1 = c1x * c1x + c1y * c1y + c1z * c1z;
    float n2 = c2x * c2x + c2y * c2y + c2z * c2z;
    float bx = c0x, by = c0y, bz = c0z, bnm = n0;
    if (n1 > bnm) { bx = c1x; by = c1y; bz = c1z; bnm = n1; }
    if (n2 > bnm) { bx = c2x; by = c2y; bz = c2z; bnm = n2; }
    if (bnm < 1e-30f) { vx = 1.0f; vy = 0.0f; vz = 0.0f; return; }
    float inv = rsqrtf(bnm);
    vx = bx * inv; vy = by * inv; vz = bz * inv;
}

__global__ void zero_out_kernel(float* __restrict__ out) {
    if (threadIdx.x == 0) out[0] = 0.0f;
}

// One block = 128 queries of ONE cloud (blockIdx.z) of one batch; full-cloud
// scan split across 16 waves (segment each). 66 KB LDS + <=64 VGPR ->
// 2 blocks/CU (grid 512 = 2/CU) -> 8 waves/SIMD: the occupancy experiment,
// this time inside the register budget. Merge buffer aliases dead pts LDS;
// covariance gathers from global (L2-hot). Per-CU VALU work == round-2.
__global__ __launch_bounds__(TPB, 8) void knn_normals(
    const float* __restrict__ pred, const float* __restrict__ gt) {
    __shared__ float4 pts[NPTS + 8];                 // 64 KiB + prefetch pad
    float* keybuf = (float*)pts;                     // aliased after scan

    const int b = blockIdx.y;
    const int cloud = blockIdx.z;
    const float* __restrict__ base = (cloud ? gt : pred) + b * 3 * NPTS;
    const int tid = threadIdx.x;
    const int lane = tid & 63;
    const int w = tid >> 6;           // wave id = segment id (0..15)
    const int s0 = w * SEGC;          // wave-uniform segment offset
    const int qbase = blockIdx.x * QPB;

    // stage cloud (x, y, z, |p|^2)
    for (int i = tid; i < NPTS; i += TPB) {
        float x = base[i];
        float y = base[NPTS + i];
        float z = base[2 * NPTS + i];
        pts[i] = make_float4(x, y, z, fmaf(x, x, fmaf(y, y, z * z)));
    }
    __syncthreads();

    // query coefficients from staged LDS
    const int q0 = qbase + lane;
    const float a0x = -2.0f * pts[q0].x,      a0y = -2.0f * pts[q0].y,      a0z = -2.0f * pts[q0].z;
    const float a1x = -2.0f * pts[q0 + 64].x, a1y = -2.0f * pts[q0 + 64].y, a1z = -2.0f * pts[q0 + 64].z;

    float kq0[KNN], kq1[KNN];
#pragma unroll
    for (int j = 0; j < KNN; ++j) { kq0[j] = FLT_MAX; kq1[j] = FLT_MAX; }

    // scan: register double-buffer 2+2 float4 (16 VGPR), sched_barrier fenced
    {
        const unsigned gb = (unsigned)s0;
        float4 A0, A1, B0, B1;
        LOAD2(A, s0);
        __builtin_amdgcn_sched_barrier(0);
        for (int c = 0; c < SEGC; c += 4) {
            LOAD2(B, s0 + c + 2);
            __builtin_amdgcn_sched_barrier(0);
            PROC2(A, gb + (unsigned)c);
            __builtin_amdgcn_sched_barrier(0);
            LOAD2(A, s0 + c + 4);     /* last iter reads pad (w15: 4096,4097) */
            __builtin_amdgcn_sched_barrier(0);
            PROC2(B, gb + (unsigned)c + 2u);
            __builtin_amdgcn_sched_barrier(0);
        }
    }
    __syncthreads();   // all waves done scanning before keybuf aliases pts

    // tree merge 16->8->4->2->1 in aliased keybuf (8 rows x 21 x 64 = 43 KB)
    for (int half = WAVES / 2; half >= 1; half >>= 1) {
        if (w >= half && w < 2 * half) {
            float* dst = keybuf + ((w - half) * 64 + lane) * KB_STRIDE;
#pragma unroll
            for (int j = 0; j < KNN; ++j) { dst[j] = kq0[j]; dst[KNN + j] = kq1[j]; }
        }
        __syncthreads();
        if (w < half) {
            const float* src = keybuf + (w * 64 + lane) * KB_STRIDE;
#pragma unroll
            for (int j = 0; j < KNN; ++j) {
                float s0v = src[j], s1v = src[KNN + j];
                INSERT(kq0, s0v);
                INSERT(kq1, s1v);
            }
        }
        __syncthreads();
    }

    // tail: wave 0 publishes final top-10s; waves 0..1 each finish one query
    if (w == 0) {
        float* dst = keybuf + lane * KB_STRIDE;
#pragma unroll
        for (int j = 0; j < KNN; ++j) { dst[j] = kq0[j]; dst[KNN + j] = kq1[j]; }
    }
    __syncthreads();
    if (w < Q) {
        const float* src = keybuf + lane * KB_STRIDE + w * KNN;
        float sx = 0.f, sy = 0.f, sz = 0.f;
        float sxx = 0.f, sxy = 0.f, sxz = 0.f;
        float syy = 0.f, syz = 0.f, szz = 0.f;
#pragma unroll
        for (int j = 0; j < KNN; ++j) {
            int idx = (int)(__float_as_uint(src[j]) & 0xFFFu);
            float x = base[idx];                       // global gather (L2-hot);
            float y = base[NPTS + idx];                // pts LDS is dead (aliased)
            float z = base[2 * NPTS + idx];
            sx += x; sy += y; sz += z;
            sxx = fmaf(x, x, sxx); sxy = fmaf(x, y, sxy); sxz = fmaf(x, z, sxz);
            syy = fmaf(y, y, syy); syz = fmaf(y, z, syz); szz = fmaf(z, z, szz);
        }
        const float iK = 1.0f / KNN;
        float mx = sx * iK, my = sy * iK, mz = sz * iK;
        float vx, vy, vz;
        smallest_eigvec(sxx * iK - mx * mx, sxy * iK - mx * my,
                        sxz * iK - mx * mz, syy * iK - my * my,
                        syz * iK - my * mz, szz * iK - mz * mz,
                        vx, vy, vz);
        g_nrm[(cloud * BATCH + b) * NPTS + qbase + w * 64 + lane] = make_float4(vx, vy, vz, 0.f);
    }
}

// loss over 32768 point pairs; one wave-sum atomic per 64 lanes
__global__ __launch_bounds__(256) void cos_loss_kernel(float* __restrict__ out) {
    const int i = blockIdx.x * 256 + threadIdx.x;     // grid sized exactly BN
    float4 p = g_nrm[i];
    float4 g = g_nrm[BN + i];
    float dot = p.x * g.x + p.y * g.y + p.z * g.z;
    float npn = sqrtf(p.x * p.x + p.y * p.y + p.z * p.z);
    float ngn = sqrtf(g.x * g.x + g.y * g.y + g.z * g.z);
    float acc = 1.0f - fabsf(dot / fmaxf(npn * ngn, 1e-8f));
    for (int off = 32; off > 0; off >>= 1) acc += __shfl_down(acc, off);
    if ((threadIdx.x & 63) == 0) atomicAdd(out, acc * (1.0f / (float)BN));
}

extern "C" void kernel_launch(void* const* d_in, const int* in_sizes, int n_in,
                              void* d_out, int out_size, void* d_ws, size_t ws_size,
                              hipStream_t stream) {
    const float* pred = (const float*)d_in[0];
    const float* gt = (const float*)d_in[1];
    float* out = (float*)d_out;

    zero_out_kernel<<<1, 64, 0, stream>>>(out);
    dim3 grid(NPTS / QPB, BATCH, 2);  // 32 x 8 x 2 = 512 blocks = 2/CU
    knn_normals<<<grid, TPB, 0, stream>>>(pred, gt);
    cos_loss_kernel<<<dim3(BN / 256), 256, 0, stream>>>(out);
}